// Round 3
// baseline (1829.268 us; speedup 1.0000x reference)
//
#include <hip/hip_runtime.h>
#include <hip/hip_fp16.h>

typedef unsigned int uint32;

__device__ __forceinline__ float h2f(__half v) { return __half2float(v); }
__device__ __forceinline__ __half f2h(float v) { return __float2half(v); }

// ---------------------------------------------------------------------------
// K1: t1 = leaky_relu(x @ conv1_w + conv1_b)  (131072,180)->(131072,36) f16
// ---------------------------------------------------------------------------
__global__ __launch_bounds__(256) void k1_conv1(const float* __restrict__ X,
                                                const float* __restrict__ W1,
                                                const float* __restrict__ B1,
                                                __half* __restrict__ T1) {
  __shared__ float ws[180 * 36];
  for (int i = threadIdx.x; i < 180 * 36; i += 256) ws[i] = W1[i];
  __syncthreads();
  int gid = blockIdx.x * 256 + threadIdx.x;
  int q = gid / 36, co = gid % 36;
  const float* xr = X + (size_t)q * 4 * 180;
  float a0 = 0.f, a1 = 0.f, a2 = 0.f, a3 = 0.f;
#pragma unroll 4
  for (int c = 0; c < 180; ++c) {
    float w = ws[c * 36 + co];
    a0 += xr[c] * w;
    a1 += xr[180 + c] * w;
    a2 += xr[360 + c] * w;
    a3 += xr[540 + c] * w;
  }
  float bb = B1[co];
  a0 += bb; a1 += bb; a2 += bb; a3 += bb;
  __half* o = T1 + (size_t)q * 4 * 36 + co;
  o[0]   = f2h(a0 > 0.f ? a0 : 0.2f * a0);
  o[36]  = f2h(a1 > 0.f ? a1 : 0.2f * a1);
  o[72]  = f2h(a2 > 0.f ? a2 : 0.2f * a2);
  o[108] = f2h(a3 > 0.f ? a3 : 0.2f * a3);
}

// ---------------------------------------------------------------------------
// K2: t2 = leaky_relu(conv3x3(t1) + conv2_b), SAME. f16 in/out.
// ---------------------------------------------------------------------------
__global__ __launch_bounds__(256) void k2_conv2(const __half* __restrict__ T1,
                                                const float* __restrict__ W2,
                                                const float* __restrict__ B2,
                                                __half* __restrict__ T2) {
  __shared__ float ws[9 * 36 * 36];
  for (int i = threadIdx.x; i < 9 * 36 * 36; i += 256) ws[i] = W2[i];
  __syncthreads();
  int gid = blockIdx.x * 256 + threadIdx.x;
  int q = gid / 36, co = gid % 36;
  int p0 = q * 4;
  int b = p0 >> 16, rem = p0 & 65535, y = rem >> 8, x0 = rem & 255;
  float a0 = 0.f, a1 = 0.f, a2 = 0.f, a3 = 0.f;
  for (int kh = 0; kh < 3; ++kh) {
    int ry = y + kh - 1;
    if ((unsigned)ry >= 256u) continue;
    const __half* rowp = T1 + ((size_t)(b * 256 + ry)) * 256 * 36;
    for (int ci = 0; ci < 36; ++ci) {
      float rv[6];
#pragma unroll
      for (int j = 0; j < 6; ++j) {
        int xx = x0 - 1 + j;
        rv[j] = ((unsigned)xx < 256u) ? h2f(rowp[xx * 36 + ci]) : 0.f;
      }
      const float* wk = ws + (kh * 3) * 1296 + ci * 36 + co;
#pragma unroll
      for (int kw = 0; kw < 3; ++kw) {
        float w = wk[kw * 1296];
        a0 += rv[kw] * w; a1 += rv[kw + 1] * w;
        a2 += rv[kw + 2] * w; a3 += rv[kw + 3] * w;
      }
    }
  }
  float bb = B2[co];
  a0 += bb; a1 += bb; a2 += bb; a3 += bb;
  __half* o = T2 + (size_t)p0 * 36 + co;
  o[0]   = f2h(a0 > 0.f ? a0 : 0.2f * a0);
  o[36]  = f2h(a1 > 0.f ? a1 : 0.2f * a1);
  o[72]  = f2h(a2 > 0.f ? a2 : 0.2f * a2);
  o[108] = f2h(a3 > 0.f ? a3 : 0.2f * a3);
}

// ---------------------------------------------------------------------------
// K3: qv = (t2 @ conv3_w + b3) * (x @ dfe_lin_w + bd), stored x64 in f16,
// windowed layout QX[wi][l][ch].
// ---------------------------------------------------------------------------
__global__ __launch_bounds__(256) void k3_qv(const float* __restrict__ X,
                                             const __half* __restrict__ T2,
                                             const float* __restrict__ W3,
                                             const float* __restrict__ B3,
                                             const float* __restrict__ WD,
                                             const float* __restrict__ BD,
                                             __half* __restrict__ QX) {
  __shared__ float ws3[36 * 180];
  for (int i = threadIdx.x; i < 36 * 180; i += 256) ws3[i] = W3[i];
  __syncthreads();
  int gid = blockIdx.x * 256 + threadIdx.x;
  int q = gid / 180, ch = gid % 180;
  int p0 = q * 4;
  const float* xr = X + (size_t)p0 * 180;
  float d0 = 0.f, d1 = 0.f, d2 = 0.f, d3 = 0.f;
#pragma unroll 4
  for (int c = 0; c < 180; ++c) {
    float w = WD[c * 180 + ch];
    d0 += xr[c] * w;
    d1 += xr[180 + c] * w;
    d2 += xr[360 + c] * w;
    d3 += xr[540 + c] * w;
  }
  const __half* tr = T2 + (size_t)p0 * 36;
  float c0 = 0.f, c1 = 0.f, c2 = 0.f, c3 = 0.f;
#pragma unroll 4
  for (int c = 0; c < 36; ++c) {
    float w = ws3[c * 180 + ch];
    c0 += h2f(tr[c]) * w; c1 += h2f(tr[36 + c]) * w;
    c2 += h2f(tr[72 + c]) * w; c3 += h2f(tr[108 + c]) * w;
  }
  float cb = B3[ch], db = BD[ch];
  int b = p0 >> 16, rem = p0 & 65535, y = rem >> 8, x0 = rem & 255;
  int wi = (b << 8) | ((y >> 4) << 4) | (x0 >> 4);
  int l0 = ((y & 15) << 4) | (x0 & 15);
  __half* qvp = QX + ((size_t)(wi * 256 + l0)) * 180 + ch;
  qvp[0]   = f2h((c0 + cb) * (d0 + db) * 64.f);
  qvp[180] = f2h((c1 + cb) * (d1 + db) * 64.f);
  qvp[360] = f2h((c2 + cb) * (d2 + db) * 64.f);
  qvp[540] = f2h((c3 + cb) * (d3 + db) * 64.f);
}

// ---------------------------------------------------------------------------
// K5a: position-bias MLP over 961 grid points -> PTAB[961][6] f32
// ---------------------------------------------------------------------------
__device__ __forceinline__ void ln_relu11(const float* p, const float* g,
                                          const float* b, float* r) {
  float m = 0.f;
#pragma unroll
  for (int j = 0; j < 11; ++j) m += p[j];
  m *= (1.0f / 11.0f);
  float v = 0.f;
#pragma unroll
  for (int j = 0; j < 11; ++j) { float d = p[j] - m; v += d * d; }
  v *= (1.0f / 11.0f);
  float inv = 1.0f / sqrtf(v + 1e-5f);
#pragma unroll
  for (int j = 0; j < 11; ++j) {
    float xn = (p[j] - m) * inv * g[j] + b[j];
    r[j] = fmaxf(xn, 0.f);
  }
}
__device__ __forceinline__ void mm11(const float* r, const float* W,
                                     const float* b, float* o) {
#pragma unroll
  for (int j2 = 0; j2 < 11; ++j2) {
    float s = b[j2];
#pragma unroll
    for (int j = 0; j < 11; ++j) s += r[j] * W[j * 11 + j2];
    o[j2] = s;
  }
}

__global__ __launch_bounds__(256) void k5a_posmlp(
    const float* PPW, const float* PPB,
    const float* LN1G, const float* LN1B, const float* M1W, const float* M1B,
    const float* LN2G, const float* LN2B, const float* M2W, const float* M2B,
    const float* LN3G, const float* LN3B, const float* M3W, const float* M3B,
    float* __restrict__ PTAB) {
  int t = blockIdx.x * 256 + threadIdx.x;
  if (t >= 961) return;
  float g0 = (float)(t / 31) - 15.0f;
  float g1 = (float)(t % 31) - 15.0f;
  float p[11], r[11];
#pragma unroll
  for (int j = 0; j < 11; ++j)
    p[j] = g0 * PPW[j] + g1 * PPW[11 + j] + PPB[j];
  ln_relu11(p, LN1G, LN1B, r);
  mm11(r, M1W, M1B, p);
  ln_relu11(p, LN2G, LN2B, r);
  mm11(r, M2W, M2B, p);
  ln_relu11(p, LN3G, LN3B, r);
#pragma unroll
  for (int h = 0; h < 6; ++h) {
    float s = M3B[h];
#pragma unroll
    for (int j = 0; j < 11; ++j) s += r[j] * M3W[j * 6 + h];
    PTAB[t * 6 + h] = s;
  }
}

// ---------------------------------------------------------------------------
// K5b: RPB[h][l][m] = mean over 2x2 of PTAB[(dr+15)*31+(dc+15)][h]
// ---------------------------------------------------------------------------
__global__ __launch_bounds__(256) void k5b_rpb(const float* __restrict__ PTAB,
                                               float* __restrict__ RPB) {
  int t = blockIdx.x * 256 + threadIdx.x;  // < 98304
  int m = t & 63;
  int l = (t >> 6) & 255;
  int h = t >> 14;
  int mh = m >> 3, mw = m & 7;
  int qr = l >> 4, qc = l & 15;
  float s = 0.f;
#pragma unroll
  for (int rh = 0; rh < 2; ++rh)
#pragma unroll
    for (int rw = 0; rw < 2; ++rw) {
      int dr = qr - (mh * 2 + rh) + 15;
      int dc = qc - (mw * 2 + rw) + 15;
      s += PTAB[(dr * 31 + dc) * 6 + h];
    }
  RPB[t] = 0.25f * s;
}

// ---------------------------------------------------------------------------
// K7a: cc[wi][c][d] = sum_l q[l][c]*v[l][d] / 256, f32 out (true scale).
// q,v staged from QX (stored x64) in 64-row f16 slabs.
// ---------------------------------------------------------------------------
__global__ __launch_bounds__(256) void k7a_cc(const __half* __restrict__ QX,
                                              float* __restrict__ CC) {
  __shared__ __half qs[64 * 90];
  __shared__ __half vs[64 * 90];
  int wi = blockIdx.x, t = threadIdx.x;
  int c0 = (t % 15) * 6, d0 = (t / 15) * 6;
  bool act = t < 225;
  float acc[36];
#pragma unroll
  for (int i = 0; i < 36; ++i) acc[i] = 0.f;
  const uint32* G = (const uint32*)(QX + (size_t)wi * 46080);
  uint32* qsw = (uint32*)qs;
  uint32* vsw = (uint32*)vs;
  for (int pass = 0; pass < 4; ++pass) {
    __syncthreads();
    for (int i = t; i < 2880; i += 256) {
      int l = i / 45, k = i % 45;
      int gw = (pass * 64 + l) * 90;
      qsw[l * 45 + k] = G[gw + k];
      vsw[l * 45 + k] = G[gw + 45 + k];
    }
    __syncthreads();
    if (act) {
      for (int l = 0; l < 64; ++l) {
        const __half2* qh = (const __half2*)&qs[l * 90 + c0];
        const __half2* vh = (const __half2*)&vs[l * 90 + d0];
        float a[6], b[6];
#pragma unroll
        for (int k = 0; k < 3; ++k) {
          __half2 x = qh[k];
          a[2 * k] = __low2float(x); a[2 * k + 1] = __high2float(x);
          __half2 y = vh[k];
          b[2 * k] = __low2float(y); b[2 * k + 1] = __high2float(y);
        }
#pragma unroll
        for (int i = 0; i < 6; ++i)
#pragma unroll
          for (int j = 0; j < 6; ++j) acc[i * 6 + j] += a[i] * b[j];
      }
    }
  }
  if (act) {
    const float s = 1.0f / (256.0f * 4096.0f);  // /256 and undo 64*64 storage
#pragma unroll
    for (int i = 0; i < 6; ++i)
#pragma unroll
      for (int j = 0; j < 6; ++j)
        CC[((size_t)(wi * 90 + c0 + i)) * 90 + d0 + j] = acc[i * 6 + j] * s;
  }
}

// ---------------------------------------------------------------------------
// KA: per window: vp (LDS, x256) from v(x64); then per (l,h):
// corr = q.vp/15 + rpb ; x_sp = corr.vp written IN PLACE over q-channels
// as 256*x_sp (f16).
// ---------------------------------------------------------------------------
__global__ __launch_bounds__(256) void kA_xsp(__half* __restrict__ QX,
                                              const float* __restrict__ RPB,
                                              const float* __restrict__ SLW,
                                              const float* __restrict__ SLB) {
  __shared__ __half vlds[256 * 90];   // 46080 B, v stored x64
  __shared__ __half vpT[6 * 15 * 64]; // 11520 B, [h][c][m], scaled x256
  int wi = blockIdx.x, t = threadIdx.x;
  __half* QW = QX + (size_t)wi * 46080;
  const uint32* G = (const uint32*)QW;
  uint32* VW = (uint32*)vlds;
  for (int i = t; i < 11520; i += 256) {
    int l = i / 45, k = i % 45;
    VW[l * 45 + k] = G[l * 90 + 45 + k];
  }
  __syncthreads();
  float w0 = SLW[0], w1 = SLW[1], w2 = SLW[2], w3 = SLW[3];
  float sb = SLB[0];
  for (int e = t; e < 5760; e += 256) {
    int m = e & 63, c = (e >> 6) % 15, h = e / 960;
    int mh = m >> 3, mw = m & 7, lb = mh * 32 + mw * 2;
    int ch = h * 15 + c;
    float s = w0 * h2f(vlds[lb * 90 + ch]) + w1 * h2f(vlds[(lb + 1) * 90 + ch])
            + w2 * h2f(vlds[(lb + 16) * 90 + ch]) + w3 * h2f(vlds[(lb + 17) * 90 + ch]);
    // s = 64*dot; vp_true*256 = s*4 + 256*sb
    vpT[ch * 64 + m] = f2h(s * 4.f + sb * 256.f);
  }
  __syncthreads();
  int l = t;
  for (int h = 0; h < 6; ++h) {
    __half* qrow = QW + l * 180 + h * 15;
    float qreg[15];
#pragma unroll
    for (int c = 0; c < 15; ++c) qreg[c] = h2f(qrow[c]);  // q*64
    float corr[64];
#pragma unroll
    for (int m = 0; m < 64; ++m) corr[m] = 0.f;
    for (int c = 0; c < 15; ++c) {
      float qc = qreg[c];
      const __half2* vp2 = (const __half2*)&vpT[(h * 15 + c) * 64];
#pragma unroll
      for (int m2 = 0; m2 < 32; ++m2) {
        __half2 vv = vp2[m2];
        corr[2 * m2]     += qc * __low2float(vv);
        corr[2 * m2 + 1] += qc * __high2float(vv);
      }
    }
    const float4* rb4 = (const float4*)(RPB + ((size_t)(h * 256 + l)) * 64);
    const float inv = 1.0f / (15.0f * 64.0f * 256.0f);
#pragma unroll
    for (int m4 = 0; m4 < 16; ++m4) {
      float4 rv = rb4[m4];
      corr[4 * m4 + 0] = corr[4 * m4 + 0] * inv + rv.x;
      corr[4 * m4 + 1] = corr[4 * m4 + 1] * inv + rv.y;
      corr[4 * m4 + 2] = corr[4 * m4 + 2] * inv + rv.z;
      corr[4 * m4 + 3] = corr[4 * m4 + 3] * inv + rv.w;
    }
    for (int c = 0; c < 15; ++c) {
      const __half2* vp2 = (const __half2*)&vpT[(h * 15 + c) * 64];
      float s = 0.f;
#pragma unroll
      for (int m2 = 0; m2 < 32; ++m2) {
        __half2 vv = vp2[m2];
        s += corr[2 * m2] * __low2float(vv) + corr[2 * m2 + 1] * __high2float(vv);
      }
      qrow[c] = f2h(s);  // corr_true * vp*256 = 256 * x_sp
    }
  }
}

// ---------------------------------------------------------------------------
// KB: per window: x_ch[l][c] = sum_d cc[c][d]*v[l][d], written IN PLACE over
// v-channels as 2^20*x_ch (f16). v(x64) + cc(x65536, f16) staged in LDS.
// ---------------------------------------------------------------------------
__global__ __launch_bounds__(256) void kB_xch(__half* __restrict__ QX,
                                              const float* __restrict__ CC) {
  __shared__ __half vlds[256 * 90];  // 46080 B
  __shared__ __half ccs[90 * 90];    // 16200 B, scaled x65536
  int wi = blockIdx.x, t = threadIdx.x;
  __half* QW = QX + (size_t)wi * 46080;
  const uint32* G = (const uint32*)QW;
  uint32* VW = (uint32*)vlds;
  for (int i = t; i < 11520; i += 256) {
    int l = i / 45, k = i % 45;
    VW[l * 45 + k] = G[l * 90 + 45 + k];
  }
  const float* ccg = CC + (size_t)wi * 8100;
  for (int i = t; i < 8100; i += 256) ccs[i] = f2h(ccg[i] * 65536.f);
  __syncthreads();
  int l = t;
  float vr[90];
  const __half2* v2 = (const __half2*)&vlds[l * 90];
#pragma unroll
  for (int k = 0; k < 45; ++k) {
    __half2 h = v2[k];
    vr[2 * k] = __low2float(h); vr[2 * k + 1] = __high2float(h);
  }
  __half* orow = QW + l * 180 + 90;
  for (int c = 0; c < 90; ++c) {
    const __half2* cr = (const __half2*)&ccs[c * 90];
    float s = 0.f;
#pragma unroll
    for (int k = 0; k < 45; ++k) {
      __half2 h = cr[k];
      s += vr[2 * k] * __low2float(h) + vr[2 * k + 1] * __high2float(h);
    }
    // s = 65536*64 * x_ch = 2^22 * x_ch ; store 2^20 * x_ch
    orow[c] = f2h(s * 0.25f);
  }
}

// ---------------------------------------------------------------------------
// K8: out = concat(x_sp/256, x_ch/2^20) @ proj_w + proj_b, window-reverse
// addressing, f32 out.
// ---------------------------------------------------------------------------
__global__ __launch_bounds__(256) void k8_proj(const __half* __restrict__ XS,
                                               const float* __restrict__ PW,
                                               const float* __restrict__ PB,
                                               float* __restrict__ OUT) {
  int gid = blockIdx.x * 256 + threadIdx.x;
  int q = gid / 180, o = gid % 180;
  int p0 = q * 4;
  int b = p0 >> 16, rem = p0 & 65535, y = rem >> 8, x0 = rem & 255;
  int wi = (b << 8) | ((y >> 4) << 4) | (x0 >> 4);
  int l0 = ((y & 15) << 4) | (x0 & 15);
  const __half* xs = XS + ((size_t)(wi * 256 + l0)) * 180;
  float a0 = 0.f, a1 = 0.f, a2 = 0.f, a3 = 0.f;   // sp part
  float e0 = 0.f, e1 = 0.f, e2 = 0.f, e3 = 0.f;   // ch part
#pragma unroll 2
  for (int c = 0; c < 90; ++c) {
    float w = PW[c * 180 + o];
    a0 += h2f(xs[c]) * w;
    a1 += h2f(xs[180 + c]) * w;
    a2 += h2f(xs[360 + c]) * w;
    a3 += h2f(xs[540 + c]) * w;
  }
#pragma unroll 2
  for (int c = 90; c < 180; ++c) {
    float w = PW[c * 180 + o];
    e0 += h2f(xs[c]) * w;
    e1 += h2f(xs[180 + c]) * w;
    e2 += h2f(xs[360 + c]) * w;
    e3 += h2f(xs[540 + c]) * w;
  }
  const float ssp = 1.0f / 256.0f;
  const float sch = 1.0f / 1048576.0f;
  float pb = PB[o];
  float* op = OUT + (size_t)p0 * 180 + o;
  op[0]   = a0 * ssp + e0 * sch + pb;
  op[180] = a1 * ssp + e1 * sch + pb;
  op[360] = a2 * ssp + e2 * sch + pb;
  op[540] = a3 * ssp + e3 * sch + pb;
}

// ---------------------------------------------------------------------------
// Workspace layout (bytes) — peak requirement 66,060,288 (63.0 MB):
//  QX  f16 [512][256][180]  @ 0            (47,185,920)  qv*64 -> XS in place
//  T1  f16 [131072][36]     @ 47,185,920   ( 9,437,184)  dead after k2
//  T2  f16 [131072][36]     @ 56,623,104   ( 9,437,184)  dead after k3
//  PTAB f32 [961*6]         @ 47,185,920   (    23,064)  over dead T1
//  RPB  f32 [6][256][64]    @ 47,212,544   (   393,216)  over dead T1
//  CC   f32 [512][90][90]   @ 47,605,760   (16,588,800)  over dead T1/T2
// ---------------------------------------------------------------------------
extern "C" void kernel_launch(void* const* d_in, const int* in_sizes, int n_in,
                              void* d_out, int out_size, void* d_ws, size_t ws_size,
                              hipStream_t stream) {
  const float* X    = (const float*)d_in[0];
  const float* W1   = (const float*)d_in[1];
  const float* B1   = (const float*)d_in[2];
  const float* W2   = (const float*)d_in[3];
  const float* B2   = (const float*)d_in[4];
  const float* W3   = (const float*)d_in[5];
  const float* B3c  = (const float*)d_in[6];
  const float* WD   = (const float*)d_in[7];
  const float* BD   = (const float*)d_in[8];
  const float* SLW  = (const float*)d_in[9];
  const float* SLB  = (const float*)d_in[10];
  const float* PPW  = (const float*)d_in[11];
  const float* PPB  = (const float*)d_in[12];
  const float* LN1G = (const float*)d_in[13];
  const float* LN1B = (const float*)d_in[14];
  const float* M1W  = (const float*)d_in[15];
  const float* M1B  = (const float*)d_in[16];
  const float* LN2G = (const float*)d_in[17];
  const float* LN2B = (const float*)d_in[18];
  const float* M2W  = (const float*)d_in[19];
  const float* M2B  = (const float*)d_in[20];
  const float* LN3G = (const float*)d_in[21];
  const float* LN3B = (const float*)d_in[22];
  const float* M3W  = (const float*)d_in[23];
  const float* M3B  = (const float*)d_in[24];
  const float* PW   = (const float*)d_in[25];
  const float* PB   = (const float*)d_in[26];
  float* OUT = (float*)d_out;

  char* ws = (char*)d_ws;
  __half* QX  = (__half*)(ws);
  __half* T1  = (__half*)(ws + 47185920);
  __half* T2  = (__half*)(ws + 56623104);
  float* PTAB = (float*)(ws + 47185920);
  float* RPB  = (float*)(ws + 47212544);
  float* CC   = (float*)(ws + 47605760);

  hipLaunchKernelGGL(k1_conv1, dim3(4608), dim3(256), 0, stream, X, W1, B1, T1);
  hipLaunchKernelGGL(k2_conv2, dim3(4608), dim3(256), 0, stream, T1, W2, B2, T2);
  hipLaunchKernelGGL(k3_qv, dim3(23040), dim3(256), 0, stream, X, T2, W3, B3c, WD, BD, QX);
  hipLaunchKernelGGL(k5a_posmlp, dim3(4), dim3(256), 0, stream,
                     PPW, PPB, LN1G, LN1B, M1W, M1B, LN2G, LN2B, M2W, M2B,
                     LN3G, LN3B, M3W, M3B, PTAB);
  hipLaunchKernelGGL(k5b_rpb, dim3(384), dim3(256), 0, stream, PTAB, RPB);
  hipLaunchKernelGGL(k7a_cc, dim3(512), dim3(256), 0, stream, QX, CC);
  hipLaunchKernelGGL(kA_xsp, dim3(512), dim3(256), 0, stream, QX, RPB, SLW, SLB);
  hipLaunchKernelGGL(kB_xch, dim3(512), dim3(256), 0, stream, QX, CC);
  hipLaunchKernelGGL(k8_proj, dim3(23040), dim3(256), 0, stream, QX, PW, PB, OUT);
}

// Round 4
// 1002.567 us; speedup vs baseline: 1.8246x; 1.8246x over previous
//
#include <hip/hip_runtime.h>
#include <hip/hip_fp16.h>

typedef unsigned int uint32;

__device__ __forceinline__ float h2f(__half v) { return __half2float(v); }
__device__ __forceinline__ __half f2h(float v) { return __float2half(v); }

// ---------------------------------------------------------------------------
// K1: t1 = leaky_relu(x @ conv1_w + conv1_b)  (131072,180)->(131072,36) f16
// Tiled GEMM: M_TILE=128, N=36, K chunks of 60. Thread tile 2x(4r x 4c),
// 144 active compute threads.
// ---------------------------------------------------------------------------
__global__ __launch_bounds__(256) void k1_conv1(const float* __restrict__ X,
                                                const float* __restrict__ W1,
                                                const float* __restrict__ B1,
                                                __half* __restrict__ T1) {
  __shared__ float sm[60 * 132 + 60 * 36];
  float* Xt = sm;              // [60][132] (128 + pad4), k-major
  float* Ws = sm + 60 * 132;   // [60][36]
  int t = threadIdx.x;
  int p0 = blockIdx.x * 128;
  bool act = t < 144;
  int r0 = (t / 9) * 4, c0 = (t % 9) * 4;
  float acc[2][16];
#pragma unroll
  for (int h = 0; h < 2; ++h)
#pragma unroll
    for (int i = 0; i < 16; ++i) acc[h][i] = 0.f;

  for (int chunk = 0; chunk < 3; ++chunk) {
    __syncthreads();
    int kc = chunk * 60;
    for (int i = t; i < 128 * 60; i += 256) {
      int m = i / 60, k = i % 60;
      Xt[k * 132 + m] = X[(size_t)(p0 + m) * 180 + kc + k];
    }
    for (int i = t; i < 60 * 36; i += 256) {
      int k = i / 36, c = i % 36;
      Ws[k * 36 + c] = W1[(kc + k) * 36 + c];
    }
    __syncthreads();
    if (act) {
      for (int k = 0; k < 60; ++k) {
        float4 a0 = *(const float4*)&Xt[k * 132 + r0];
        float4 a1 = *(const float4*)&Xt[k * 132 + r0 + 64];
        float4 b  = *(const float4*)&Ws[k * 36 + c0];
        float av0[4] = {a0.x, a0.y, a0.z, a0.w};
        float av1[4] = {a1.x, a1.y, a1.z, a1.w};
        float bv[4]  = {b.x, b.y, b.z, b.w};
#pragma unroll
        for (int i = 0; i < 4; ++i)
#pragma unroll
          for (int j = 0; j < 4; ++j) {
            acc[0][i * 4 + j] += av0[i] * bv[j];
            acc[1][i * 4 + j] += av1[i] * bv[j];
          }
      }
    }
  }
  if (!act) return;
  float bb[4];
#pragma unroll
  for (int i = 0; i < 4; ++i) bb[i] = B1[c0 + i];
#pragma unroll
  for (int h = 0; h < 2; ++h)
#pragma unroll
    for (int ri = 0; ri < 4; ++ri) {
      int p = p0 + h * 64 + r0 + ri;
      __half* o = T1 + (size_t)p * 36 + c0;
      __half2 h01, h23;
      float v0 = acc[h][ri * 4 + 0] + bb[0];
      float v1 = acc[h][ri * 4 + 1] + bb[1];
      float v2 = acc[h][ri * 4 + 2] + bb[2];
      float v3 = acc[h][ri * 4 + 3] + bb[3];
      h01.x = f2h(v0 > 0.f ? v0 : 0.2f * v0);
      h01.y = f2h(v1 > 0.f ? v1 : 0.2f * v1);
      h23.x = f2h(v2 > 0.f ? v2 : 0.2f * v2);
      h23.y = f2h(v3 > 0.f ? v3 : 0.2f * v3);
      *(__half2*)o = h01;
      *(__half2*)(o + 2) = h23;
    }
}

// ---------------------------------------------------------------------------
// K2: t2 = leaky_relu(conv3x3(t1) + conv2_b), SAME. Tiled: block = 64 px
// (one y-row segment) x 36 co. Input halo staged in LDS [3][68][37-pad],
// weights in LDS. Thread tile 4 px x 4 co, 144 active.
// ---------------------------------------------------------------------------
__global__ __launch_bounds__(256) void k2_conv2(const __half* __restrict__ T1,
                                                const float* __restrict__ W2,
                                                const float* __restrict__ B2,
                                                __half* __restrict__ T2) {
  __shared__ float ins[3 * 68 * 37];   // [kh][xx][ci], stride 37
  __shared__ float ws2[9 * 36 * 36];   // [kh*3+kw][ci][co]
  int t = threadIdx.x;
  int p0 = blockIdx.x * 64;
  int b = p0 >> 16, y = (p0 >> 8) & 255, x0 = p0 & 255;
  for (int i = t; i < 11664; i += 256) ws2[i] = W2[i];
  for (int i = t; i < 3 * 66 * 36; i += 256) {
    int kh = i / 2376, rem = i % 2376;
    int xx = rem / 36, ci = rem % 36;
    int ry = y + kh - 1, gx = x0 + xx - 1;
    float v = 0.f;
    if ((unsigned)ry < 256u && (unsigned)gx < 256u)
      v = h2f(T1[((size_t)(b * 256 + ry) * 256 + gx) * 36 + ci]);
    ins[kh * 2516 + xx * 37 + ci] = v;
  }
  __syncthreads();
  bool act = t < 144;
  if (!act) return;
  int pl = (t / 9) * 4, c0 = (t % 9) * 4;
  float acc[16];
#pragma unroll
  for (int i = 0; i < 16; ++i) acc[i] = 0.f;
  for (int kh = 0; kh < 3; ++kh) {
    const float* base = ins + kh * 2516;
    for (int ci = 0; ci < 36; ++ci) {
      float rv[6];
#pragma unroll
      for (int u = 0; u < 6; ++u) rv[u] = base[(pl + u) * 37 + ci];
#pragma unroll
      for (int kw = 0; kw < 3; ++kw) {
        float4 w = *(const float4*)&ws2[((kh * 3 + kw) * 36 + ci) * 36 + c0];
        float wv[4] = {w.x, w.y, w.z, w.w};
#pragma unroll
        for (int jj = 0; jj < 4; ++jj)
#pragma unroll
          for (int i2 = 0; i2 < 4; ++i2)
            acc[jj * 4 + i2] += rv[jj + kw] * wv[i2];
      }
    }
  }
  float bb[4];
#pragma unroll
  for (int i = 0; i < 4; ++i) bb[i] = B2[c0 + i];
#pragma unroll
  for (int jj = 0; jj < 4; ++jj) {
    int p = p0 + pl + jj;
    __half* o = T2 + (size_t)p * 36 + c0;
    float v0 = acc[jj * 4 + 0] + bb[0];
    float v1 = acc[jj * 4 + 1] + bb[1];
    float v2 = acc[jj * 4 + 2] + bb[2];
    float v3 = acc[jj * 4 + 3] + bb[3];
    __half2 h01, h23;
    h01.x = f2h(v0 > 0.f ? v0 : 0.2f * v0);
    h01.y = f2h(v1 > 0.f ? v1 : 0.2f * v1);
    h23.x = f2h(v2 > 0.f ? v2 : 0.2f * v2);
    h23.y = f2h(v3 > 0.f ? v3 : 0.2f * v3);
    *(__half2*)o = h01;
    *(__half2*)(o + 2) = h23;
  }
}

// ---------------------------------------------------------------------------
// K3: qv = (t2 @ conv3_w + b3) * (x @ dfe_lin_w + bd), stored x64 f16,
// windowed layout QX[wi][l][ch]. Tiled GEMM: 64x60 tile, thread 4x4,
// dual accumulators (dfe K=180 in 3 chunks; conv3 K=36).
// ---------------------------------------------------------------------------
__global__ __launch_bounds__(256) void k3_qv(const float* __restrict__ X,
                                             const __half* __restrict__ T2,
                                             const float* __restrict__ W3,
                                             const float* __restrict__ B3,
                                             const float* __restrict__ WD,
                                             const float* __restrict__ BD,
                                             __half* __restrict__ QX) {
  __shared__ float sm[60 * 68 + 60 * 60];  // 30720 B, unioned stages
  float* Xt = sm;              // [60][68] k-major
  float* Wd = sm + 60 * 68;    // [60][60]
  float* T2t = sm;             // [36][68] (reuse)
  float* W3s = sm + 36 * 68;   // [36][60] (reuse)
  int t = threadIdx.x;
  int bm = blockIdx.x / 3, bn = blockIdx.x % 3;
  int p0 = bm * 64, n0 = bn * 60;
  bool act = t < 240;
  int r0 = (t / 15) * 4, c0 = (t % 15) * 4;
  float accD[16], accC[16];
#pragma unroll
  for (int i = 0; i < 16; ++i) { accD[i] = 0.f; accC[i] = 0.f; }

  // conv3 part first (uses T2t/W3s region)
  for (int i = t; i < 64 * 36; i += 256) {
    int m = i / 36, k = i % 36;
    T2t[k * 68 + m] = h2f(T2[(size_t)(p0 + m) * 36 + k]);
  }
  for (int i = t; i < 36 * 60; i += 256) {
    int k = i / 60, c = i % 60;
    W3s[k * 60 + c] = W3[k * 180 + n0 + c];
  }
  __syncthreads();
  if (act) {
    for (int k = 0; k < 36; ++k) {
      float4 a = *(const float4*)&T2t[k * 68 + r0];
      float4 b = *(const float4*)&W3s[k * 60 + c0];
      float av[4] = {a.x, a.y, a.z, a.w};
      float bv[4] = {b.x, b.y, b.z, b.w};
#pragma unroll
      for (int i = 0; i < 4; ++i)
#pragma unroll
        for (int j = 0; j < 4; ++j) accC[i * 4 + j] += av[i] * bv[j];
    }
  }
  // dfe part: K=180 in 3 chunks of 60
  for (int chunk = 0; chunk < 3; ++chunk) {
    __syncthreads();
    int kc = chunk * 60;
    for (int i = t; i < 64 * 60; i += 256) {
      int m = i / 60, k = i % 60;
      Xt[k * 68 + m] = X[(size_t)(p0 + m) * 180 + kc + k];
    }
    for (int i = t; i < 60 * 60; i += 256) {
      int k = i / 60, c = i % 60;
      Wd[k * 60 + c] = WD[(size_t)(kc + k) * 180 + n0 + c];
    }
    __syncthreads();
    if (act) {
      for (int k = 0; k < 60; ++k) {
        float4 a = *(const float4*)&Xt[k * 68 + r0];
        float4 b = *(const float4*)&Wd[k * 60 + c0];
        float av[4] = {a.x, a.y, a.z, a.w};
        float bv[4] = {b.x, b.y, b.z, b.w};
#pragma unroll
        for (int i = 0; i < 4; ++i)
#pragma unroll
          for (int j = 0; j < 4; ++j) accD[i * 4 + j] += av[i] * bv[j];
      }
    }
  }
  if (!act) return;
  float cb[4], db[4];
#pragma unroll
  for (int i = 0; i < 4; ++i) {
    cb[i] = B3[n0 + c0 + i];
    db[i] = BD[n0 + c0 + i];
  }
#pragma unroll
  for (int ri = 0; ri < 4; ++ri) {
    int p = p0 + r0 + ri;
    int b = p >> 16, y = (p >> 8) & 255, x = p & 255;
    int wi = (b << 8) | ((y >> 4) << 4) | (x >> 4);
    int l = ((y & 15) << 4) | (x & 15);
    __half* o = QX + ((size_t)(wi * 256 + l)) * 180 + n0 + c0;
    __half2 h01, h23;
    h01.x = f2h((accC[ri * 4 + 0] + cb[0]) * (accD[ri * 4 + 0] + db[0]) * 64.f);
    h01.y = f2h((accC[ri * 4 + 1] + cb[1]) * (accD[ri * 4 + 1] + db[1]) * 64.f);
    h23.x = f2h((accC[ri * 4 + 2] + cb[2]) * (accD[ri * 4 + 2] + db[2]) * 64.f);
    h23.y = f2h((accC[ri * 4 + 3] + cb[3]) * (accD[ri * 4 + 3] + db[3]) * 64.f);
    *(__half2*)o = h01;
    *(__half2*)(o + 2) = h23;
  }
}

// ---------------------------------------------------------------------------
// K5a: position-bias MLP over 961 grid points -> PTAB[961][6] f32
// ---------------------------------------------------------------------------
__device__ __forceinline__ void ln_relu11(const float* p, const float* g,
                                          const float* b, float* r) {
  float m = 0.f;
#pragma unroll
  for (int j = 0; j < 11; ++j) m += p[j];
  m *= (1.0f / 11.0f);
  float v = 0.f;
#pragma unroll
  for (int j = 0; j < 11; ++j) { float d = p[j] - m; v += d * d; }
  v *= (1.0f / 11.0f);
  float inv = 1.0f / sqrtf(v + 1e-5f);
#pragma unroll
  for (int j = 0; j < 11; ++j) {
    float xn = (p[j] - m) * inv * g[j] + b[j];
    r[j] = fmaxf(xn, 0.f);
  }
}
__device__ __forceinline__ void mm11(const float* r, const float* W,
                                     const float* b, float* o) {
#pragma unroll
  for (int j2 = 0; j2 < 11; ++j2) {
    float s = b[j2];
#pragma unroll
    for (int j = 0; j < 11; ++j) s += r[j] * W[j * 11 + j2];
    o[j2] = s;
  }
}

__global__ __launch_bounds__(256) void k5a_posmlp(
    const float* PPW, const float* PPB,
    const float* LN1G, const float* LN1B, const float* M1W, const float* M1B,
    const float* LN2G, const float* LN2B, const float* M2W, const float* M2B,
    const float* LN3G, const float* LN3B, const float* M3W, const float* M3B,
    float* __restrict__ PTAB) {
  int t = blockIdx.x * 256 + threadIdx.x;
  if (t >= 961) return;
  float g0 = (float)(t / 31) - 15.0f;
  float g1 = (float)(t % 31) - 15.0f;
  float p[11], r[11];
#pragma unroll
  for (int j = 0; j < 11; ++j)
    p[j] = g0 * PPW[j] + g1 * PPW[11 + j] + PPB[j];
  ln_relu11(p, LN1G, LN1B, r);
  mm11(r, M1W, M1B, p);
  ln_relu11(p, LN2G, LN2B, r);
  mm11(r, M2W, M2B, p);
  ln_relu11(p, LN3G, LN3B, r);
#pragma unroll
  for (int h = 0; h < 6; ++h) {
    float s = M3B[h];
#pragma unroll
    for (int j = 0; j < 11; ++j) s += r[j] * M3W[j * 6 + h];
    PTAB[t * 6 + h] = s;
  }
}

// ---------------------------------------------------------------------------
// K5b: RPB[h][l][m] = mean over 2x2 of PTAB[(dr+15)*31+(dc+15)][h]
// ---------------------------------------------------------------------------
__global__ __launch_bounds__(256) void k5b_rpb(const float* __restrict__ PTAB,
                                               float* __restrict__ RPB) {
  int t = blockIdx.x * 256 + threadIdx.x;  // < 98304
  int m = t & 63;
  int l = (t >> 6) & 255;
  int h = t >> 14;
  int mh = m >> 3, mw = m & 7;
  int qr = l >> 4, qc = l & 15;
  float s = 0.f;
#pragma unroll
  for (int rh = 0; rh < 2; ++rh)
#pragma unroll
    for (int rw = 0; rw < 2; ++rw) {
      int dr = qr - (mh * 2 + rh) + 15;
      int dc = qc - (mw * 2 + rw) + 15;
      s += PTAB[(dr * 31 + dc) * 6 + h];
    }
  RPB[t] = 0.25f * s;
}

// ---------------------------------------------------------------------------
// K7a: cc[wi][c][d] = sum_l q[l][c]*v[l][d] / 256, f32 out (true scale).
// q,v staged from QX (stored x64) in 64-row f16 slabs.
// ---------------------------------------------------------------------------
__global__ __launch_bounds__(256) void k7a_cc(const __half* __restrict__ QX,
                                              float* __restrict__ CC) {
  __shared__ __half qs[64 * 90];
  __shared__ __half vs[64 * 90];
  int wi = blockIdx.x, t = threadIdx.x;
  int c0 = (t % 15) * 6, d0 = (t / 15) * 6;
  bool act = t < 225;
  float acc[36];
#pragma unroll
  for (int i = 0; i < 36; ++i) acc[i] = 0.f;
  const uint32* G = (const uint32*)(QX + (size_t)wi * 46080);
  uint32* qsw = (uint32*)qs;
  uint32* vsw = (uint32*)vs;
  for (int pass = 0; pass < 4; ++pass) {
    __syncthreads();
    for (int i = t; i < 2880; i += 256) {
      int l = i / 45, k = i % 45;
      int gw = (pass * 64 + l) * 90;
      qsw[l * 45 + k] = G[gw + k];
      vsw[l * 45 + k] = G[gw + 45 + k];
    }
    __syncthreads();
    if (act) {
      for (int l = 0; l < 64; ++l) {
        const __half2* qh = (const __half2*)&qs[l * 90 + c0];
        const __half2* vh = (const __half2*)&vs[l * 90 + d0];
        float a[6], b[6];
#pragma unroll
        for (int k = 0; k < 3; ++k) {
          __half2 x = qh[k];
          a[2 * k] = __low2float(x); a[2 * k + 1] = __high2float(x);
          __half2 y = vh[k];
          b[2 * k] = __low2float(y); b[2 * k + 1] = __high2float(y);
        }
#pragma unroll
        for (int i = 0; i < 6; ++i)
#pragma unroll
          for (int j = 0; j < 6; ++j) acc[i * 6 + j] += a[i] * b[j];
      }
    }
  }
  if (act) {
    const float s = 1.0f / (256.0f * 4096.0f);  // /256 and undo 64*64 storage
#pragma unroll
    for (int i = 0; i < 6; ++i)
#pragma unroll
      for (int j = 0; j < 6; ++j)
        CC[((size_t)(wi * 90 + c0 + i)) * 90 + d0 + j] = acc[i * 6 + j] * s;
  }
}

// ---------------------------------------------------------------------------
// KA: per window: vp (LDS, x256) from v(x64); then per (l,h):
// corr = q.vp/15 + rpb ; x_sp = corr.vp written IN PLACE over q-channels
// as 256*x_sp (f16).
// ---------------------------------------------------------------------------
__global__ __launch_bounds__(256) void kA_xsp(__half* __restrict__ QX,
                                              const float* __restrict__ RPB,
                                              const float* __restrict__ SLW,
                                              const float* __restrict__ SLB) {
  __shared__ __half vlds[256 * 90];   // 46080 B, v stored x64
  __shared__ __half vpT[6 * 15 * 64]; // 11520 B, [h][c][m], scaled x256
  int wi = blockIdx.x, t = threadIdx.x;
  __half* QW = QX + (size_t)wi * 46080;
  const uint32* G = (const uint32*)QW;
  uint32* VW = (uint32*)vlds;
  for (int i = t; i < 11520; i += 256) {
    int l = i / 45, k = i % 45;
    VW[l * 45 + k] = G[l * 90 + 45 + k];
  }
  __syncthreads();
  float w0 = SLW[0], w1 = SLW[1], w2 = SLW[2], w3 = SLW[3];
  float sb = SLB[0];
  for (int e = t; e < 5760; e += 256) {
    int m = e & 63, c = (e >> 6) % 15, h = e / 960;
    int mh = m >> 3, mw = m & 7, lb = mh * 32 + mw * 2;
    int ch = h * 15 + c;
    float s = w0 * h2f(vlds[lb * 90 + ch]) + w1 * h2f(vlds[(lb + 1) * 90 + ch])
            + w2 * h2f(vlds[(lb + 16) * 90 + ch]) + w3 * h2f(vlds[(lb + 17) * 90 + ch]);
    // s = 64*dot; vp_true*256 = s*4 + 256*sb
    vpT[ch * 64 + m] = f2h(s * 4.f + sb * 256.f);
  }
  __syncthreads();
  int l = t;
  for (int h = 0; h < 6; ++h) {
    __half* qrow = QW + l * 180 + h * 15;
    float qreg[15];
#pragma unroll
    for (int c = 0; c < 15; ++c) qreg[c] = h2f(qrow[c]);  // q*64
    float corr[64];
#pragma unroll
    for (int m = 0; m < 64; ++m) corr[m] = 0.f;
    for (int c = 0; c < 15; ++c) {
      float qc = qreg[c];
      const __half2* vp2 = (const __half2*)&vpT[(h * 15 + c) * 64];
#pragma unroll
      for (int m2 = 0; m2 < 32; ++m2) {
        __half2 vv = vp2[m2];
        corr[2 * m2]     += qc * __low2float(vv);
        corr[2 * m2 + 1] += qc * __high2float(vv);
      }
    }
    const float4* rb4 = (const float4*)(RPB + ((size_t)(h * 256 + l)) * 64);
    const float inv = 1.0f / (15.0f * 64.0f * 256.0f);
#pragma unroll
    for (int m4 = 0; m4 < 16; ++m4) {
      float4 rv = rb4[m4];
      corr[4 * m4 + 0] = corr[4 * m4 + 0] * inv + rv.x;
      corr[4 * m4 + 1] = corr[4 * m4 + 1] * inv + rv.y;
      corr[4 * m4 + 2] = corr[4 * m4 + 2] * inv + rv.z;
      corr[4 * m4 + 3] = corr[4 * m4 + 3] * inv + rv.w;
    }
    for (int c = 0; c < 15; ++c) {
      const __half2* vp2 = (const __half2*)&vpT[(h * 15 + c) * 64];
      float s = 0.f;
#pragma unroll
      for (int m2 = 0; m2 < 32; ++m2) {
        __half2 vv = vp2[m2];
        s += corr[2 * m2] * __low2float(vv) + corr[2 * m2 + 1] * __high2float(vv);
      }
      qrow[c] = f2h(s);  // corr_true * vp*256 = 256 * x_sp
    }
  }
}

// ---------------------------------------------------------------------------
// KB: per window: x_ch[l][c] = sum_d cc[c][d]*v[l][d], written IN PLACE over
// v-channels as 2^20*x_ch (f16). v(x64) + cc(x65536, f16) staged in LDS.
// ---------------------------------------------------------------------------
__global__ __launch_bounds__(256) void kB_xch(__half* __restrict__ QX,
                                              const float* __restrict__ CC) {
  __shared__ __half vlds[256 * 90];  // 46080 B
  __shared__ __half ccs[90 * 90];    // 16200 B, scaled x65536
  int wi = blockIdx.x, t = threadIdx.x;
  __half* QW = QX + (size_t)wi * 46080;
  const uint32* G = (const uint32*)QW;
  uint32* VW = (uint32*)vlds;
  for (int i = t; i < 11520; i += 256) {
    int l = i / 45, k = i % 45;
    VW[l * 45 + k] = G[l * 90 + 45 + k];
  }
  const float* ccg = CC + (size_t)wi * 8100;
  for (int i = t; i < 8100; i += 256) ccs[i] = f2h(ccg[i] * 65536.f);
  __syncthreads();
  int l = t;
  float vr[90];
  const __half2* v2 = (const __half2*)&vlds[l * 90];
#pragma unroll
  for (int k = 0; k < 45; ++k) {
    __half2 h = v2[k];
    vr[2 * k] = __low2float(h); vr[2 * k + 1] = __high2float(h);
  }
  __half* orow = QW + l * 180 + 90;
  for (int c = 0; c < 90; ++c) {
    const __half2* cr = (const __half2*)&ccs[c * 90];
    float s = 0.f;
#pragma unroll
    for (int k = 0; k < 45; ++k) {
      __half2 h = cr[k];
      s += vr[2 * k] * __low2float(h) + vr[2 * k + 1] * __high2float(h);
    }
    // s = 65536*64 * x_ch = 2^22 * x_ch ; store 2^20 * x_ch
    orow[c] = f2h(s * 0.25f);
  }
}

// ---------------------------------------------------------------------------
// K8: out = concat(x_sp/256, x_ch/2^20) @ proj_w + proj_b, f32 out.
// Tiled GEMM over windowed rows w: 64x60 tile, thread 4x4, K=180 in 3
// chunks; per-k scale folded into A staging; window-reverse on store.
// ---------------------------------------------------------------------------
__global__ __launch_bounds__(256) void k8_proj(const __half* __restrict__ XS,
                                               const float* __restrict__ PW,
                                               const float* __restrict__ PB,
                                               float* __restrict__ OUT) {
  __shared__ float sm[60 * 68 + 60 * 60];
  float* At = sm;            // [60][68]
  float* Pw = sm + 60 * 68;  // [60][60]
  int t = threadIdx.x;
  int bm = blockIdx.x / 3, bn = blockIdx.x % 3;
  int w0r = bm * 64, n0 = bn * 60;
  bool act = t < 240;
  int r0 = (t / 15) * 4, c0 = (t % 15) * 4;
  float acc[16];
#pragma unroll
  for (int i = 0; i < 16; ++i) acc[i] = 0.f;
  const float ssp = 1.0f / 256.0f, sch = 1.0f / 1048576.0f;
  for (int chunk = 0; chunk < 3; ++chunk) {
    __syncthreads();
    int kc = chunk * 60;
    for (int i = t; i < 64 * 60; i += 256) {
      int m = i / 60, k = i % 60;
      int c = kc + k;
      float s = (c < 90) ? ssp : sch;
      At[k * 68 + m] = h2f(XS[(size_t)(w0r + m) * 180 + c]) * s;
    }
    for (int i = t; i < 60 * 60; i += 256) {
      int k = i / 60, c = i % 60;
      Pw[k * 60 + c] = PW[(size_t)(kc + k) * 180 + n0 + c];
    }
    __syncthreads();
    if (act) {
      for (int k = 0; k < 60; ++k) {
        float4 a = *(const float4*)&At[k * 68 + r0];
        float4 b = *(const float4*)&Pw[k * 60 + c0];
        float av[4] = {a.x, a.y, a.z, a.w};
        float bv[4] = {b.x, b.y, b.z, b.w};
#pragma unroll
        for (int i = 0; i < 4; ++i)
#pragma unroll
          for (int j = 0; j < 4; ++j) acc[i * 4 + j] += av[i] * bv[j];
      }
    }
  }
  if (!act) return;
  float pb[4];
#pragma unroll
  for (int i = 0; i < 4; ++i) pb[i] = PB[n0 + c0 + i];
#pragma unroll
  for (int ri = 0; ri < 4; ++ri) {
    int w = w0r + r0 + ri;
    int wi = w >> 8, l = w & 255;
    int b = wi >> 8, wy = (wi >> 4) & 15, wx = wi & 15;
    int ly = l >> 4, lx = l & 15;
    int p = (b << 16) | (((wy << 4) | ly) << 8) | ((wx << 4) | lx);
    float4 v;
    v.x = acc[ri * 4 + 0] + pb[0];
    v.y = acc[ri * 4 + 1] + pb[1];
    v.z = acc[ri * 4 + 2] + pb[2];
    v.w = acc[ri * 4 + 3] + pb[3];
    *(float4*)(OUT + (size_t)p * 180 + n0 + c0) = v;
  }
}

// ---------------------------------------------------------------------------
// Workspace layout (bytes) — peak requirement 66,060,288 (63.0 MB):
//  QX  f16 [512][256][180]  @ 0            (47,185,920)  qv*64 -> XS in place
//  T1  f16 [131072][36]     @ 47,185,920   ( 9,437,184)  dead after k2
//  T2  f16 [131072][36]     @ 56,623,104   ( 9,437,184)  dead after k3
//  PTAB f32 [961*6]         @ 47,185,920   (    23,064)  over dead T1
//  RPB  f32 [6][256][64]    @ 47,212,544   (   393,216)  over dead T1
//  CC   f32 [512][90][90]   @ 47,605,760   (16,588,800)  over dead T1/T2
// ---------------------------------------------------------------------------
extern "C" void kernel_launch(void* const* d_in, const int* in_sizes, int n_in,
                              void* d_out, int out_size, void* d_ws, size_t ws_size,
                              hipStream_t stream) {
  const float* X    = (const float*)d_in[0];
  const float* W1   = (const float*)d_in[1];
  const float* B1   = (const float*)d_in[2];
  const float* W2   = (const float*)d_in[3];
  const float* B2   = (const float*)d_in[4];
  const float* W3   = (const float*)d_in[5];
  const float* B3c  = (const float*)d_in[6];
  const float* WD   = (const float*)d_in[7];
  const float* BD   = (const float*)d_in[8];
  const float* SLW  = (const float*)d_in[9];
  const float* SLB  = (const float*)d_in[10];
  const float* PPW  = (const float*)d_in[11];
  const float* PPB  = (const float*)d_in[12];
  const float* LN1G = (const float*)d_in[13];
  const float* LN1B = (const float*)d_in[14];
  const float* M1W  = (const float*)d_in[15];
  const float* M1B  = (const float*)d_in[16];
  const float* LN2G = (const float*)d_in[17];
  const float* LN2B = (const float*)d_in[18];
  const float* M2W  = (const float*)d_in[19];
  const float* M2B  = (const float*)d_in[20];
  const float* LN3G = (const float*)d_in[21];
  const float* LN3B = (const float*)d_in[22];
  const float* M3W  = (const float*)d_in[23];
  const float* M3B  = (const float*)d_in[24];
  const float* PW   = (const float*)d_in[25];
  const float* PB   = (const float*)d_in[26];
  float* OUT = (float*)d_out;

  char* ws = (char*)d_ws;
  __half* QX  = (__half*)(ws);
  __half* T1  = (__half*)(ws + 47185920);
  __half* T2  = (__half*)(ws + 56623104);
  float* PTAB = (float*)(ws + 47185920);
  float* RPB  = (float*)(ws + 47212544);
  float* CC   = (float*)(ws + 47605760);

  hipLaunchKernelGGL(k1_conv1, dim3(1024), dim3(256), 0, stream, X, W1, B1, T1);
  hipLaunchKernelGGL(k2_conv2, dim3(2048), dim3(256), 0, stream, T1, W2, B2, T2);
  hipLaunchKernelGGL(k3_qv, dim3(6144), dim3(256), 0, stream, X, T2, W3, B3c, WD, BD, QX);
  hipLaunchKernelGGL(k5a_posmlp, dim3(4), dim3(256), 0, stream,
                     PPW, PPB, LN1G, LN1B, M1W, M1B, LN2G, LN2B, M2W, M2B,
                     LN3G, LN3B, M3W, M3B, PTAB);
  hipLaunchKernelGGL(k5b_rpb, dim3(384), dim3(256), 0, stream, PTAB, RPB);
  hipLaunchKernelGGL(k7a_cc, dim3(512), dim3(256), 0, stream, QX, CC);
  hipLaunchKernelGGL(kA_xsp, dim3(512), dim3(256), 0, stream, QX, RPB, SLW, SLB);
  hipLaunchKernelGGL(kB_xch, dim3(512), dim3(256), 0, stream, QX, CC);
  hipLaunchKernelGGL(k8_proj, dim3(6144), dim3(256), 0, stream, QX, PW, PB, OUT);
}

// Round 5
// 798.190 us; speedup vs baseline: 2.2918x; 1.2561x over previous
//
#include <hip/hip_runtime.h>
#include <hip/hip_fp16.h>

typedef unsigned int uint32;
typedef _Float16 f16;
typedef f16 f16x8 __attribute__((ext_vector_type(8)));
typedef float f32x4 __attribute__((ext_vector_type(4)));

__device__ __forceinline__ float h2f(__half v) { return __half2float(v); }
__device__ __forceinline__ __half f2h(float v) { return __float2half(v); }

// ---------------------------------------------------------------------------
// K1: t1 = leaky_relu(x @ conv1_w + conv1_b)  (131072,180)->(131072,36) f16
// ---------------------------------------------------------------------------
__global__ __launch_bounds__(256) void k1_conv1(const float* __restrict__ X,
                                                const float* __restrict__ W1,
                                                const float* __restrict__ B1,
                                                __half* __restrict__ T1) {
  __shared__ float sm[60 * 132 + 60 * 36];
  float* Xt = sm;              // [60][132] (128 + pad4), k-major
  float* Ws = sm + 60 * 132;   // [60][36]
  int t = threadIdx.x;
  int p0 = blockIdx.x * 128;
  bool act = t < 144;
  int r0 = (t / 9) * 4, c0 = (t % 9) * 4;
  float acc[2][16];
#pragma unroll
  for (int h = 0; h < 2; ++h)
#pragma unroll
    for (int i = 0; i < 16; ++i) acc[h][i] = 0.f;

  for (int chunk = 0; chunk < 3; ++chunk) {
    __syncthreads();
    int kc = chunk * 60;
    for (int i = t; i < 128 * 60; i += 256) {
      int m = i / 60, k = i % 60;
      Xt[k * 132 + m] = X[(size_t)(p0 + m) * 180 + kc + k];
    }
    for (int i = t; i < 60 * 36; i += 256) {
      int k = i / 36, c = i % 36;
      Ws[k * 36 + c] = W1[(kc + k) * 36 + c];
    }
    __syncthreads();
    if (act) {
      for (int k = 0; k < 60; ++k) {
        float4 a0 = *(const float4*)&Xt[k * 132 + r0];
        float4 a1 = *(const float4*)&Xt[k * 132 + r0 + 64];
        float4 b  = *(const float4*)&Ws[k * 36 + c0];
        float av0[4] = {a0.x, a0.y, a0.z, a0.w};
        float av1[4] = {a1.x, a1.y, a1.z, a1.w};
        float bv[4]  = {b.x, b.y, b.z, b.w};
#pragma unroll
        for (int i = 0; i < 4; ++i)
#pragma unroll
          for (int j = 0; j < 4; ++j) {
            acc[0][i * 4 + j] += av0[i] * bv[j];
            acc[1][i * 4 + j] += av1[i] * bv[j];
          }
      }
    }
  }
  if (!act) return;
  float bb[4];
#pragma unroll
  for (int i = 0; i < 4; ++i) bb[i] = B1[c0 + i];
#pragma unroll
  for (int h = 0; h < 2; ++h)
#pragma unroll
    for (int ri = 0; ri < 4; ++ri) {
      int p = p0 + h * 64 + r0 + ri;
      __half* o = T1 + (size_t)p * 36 + c0;
      __half2 h01, h23;
      float v0 = acc[h][ri * 4 + 0] + bb[0];
      float v1 = acc[h][ri * 4 + 1] + bb[1];
      float v2 = acc[h][ri * 4 + 2] + bb[2];
      float v3 = acc[h][ri * 4 + 3] + bb[3];
      h01.x = f2h(v0 > 0.f ? v0 : 0.2f * v0);
      h01.y = f2h(v1 > 0.f ? v1 : 0.2f * v1);
      h23.x = f2h(v2 > 0.f ? v2 : 0.2f * v2);
      h23.y = f2h(v3 > 0.f ? v3 : 0.2f * v3);
      *(__half2*)o = h01;
      *(__half2*)(o + 2) = h23;
    }
}

// ---------------------------------------------------------------------------
// K2: t2 = leaky_relu(conv3x3(t1) + conv2_b), SAME. 64 px x 36 co tile.
// ---------------------------------------------------------------------------
__global__ __launch_bounds__(256) void k2_conv2(const __half* __restrict__ T1,
                                                const float* __restrict__ W2,
                                                const float* __restrict__ B2,
                                                __half* __restrict__ T2) {
  __shared__ float ins[3 * 68 * 37];   // [kh][xx][ci], stride 37
  __shared__ float ws2[9 * 36 * 36];   // [kh*3+kw][ci][co]
  int t = threadIdx.x;
  int p0 = blockIdx.x * 64;
  int b = p0 >> 16, y = (p0 >> 8) & 255, x0 = p0 & 255;
  for (int i = t; i < 11664; i += 256) ws2[i] = W2[i];
  for (int i = t; i < 3 * 66 * 36; i += 256) {
    int kh = i / 2376, rem = i % 2376;
    int xx = rem / 36, ci = rem % 36;
    int ry = y + kh - 1, gx = x0 + xx - 1;
    float v = 0.f;
    if ((unsigned)ry < 256u && (unsigned)gx < 256u)
      v = h2f(T1[((size_t)(b * 256 + ry) * 256 + gx) * 36 + ci]);
    ins[kh * 2516 + xx * 37 + ci] = v;
  }
  __syncthreads();
  bool act = t < 144;
  if (!act) return;
  int pl = (t / 9) * 4, c0 = (t % 9) * 4;
  float acc[16];
#pragma unroll
  for (int i = 0; i < 16; ++i) acc[i] = 0.f;
  for (int kh = 0; kh < 3; ++kh) {
    const float* base = ins + kh * 2516;
    for (int ci = 0; ci < 36; ++ci) {
      float rv[6];
#pragma unroll
      for (int u = 0; u < 6; ++u) rv[u] = base[(pl + u) * 37 + ci];
#pragma unroll
      for (int kw = 0; kw < 3; ++kw) {
        float4 w = *(const float4*)&ws2[((kh * 3 + kw) * 36 + ci) * 36 + c0];
        float wv[4] = {w.x, w.y, w.z, w.w};
#pragma unroll
        for (int jj = 0; jj < 4; ++jj)
#pragma unroll
          for (int i2 = 0; i2 < 4; ++i2)
            acc[jj * 4 + i2] += rv[jj + kw] * wv[i2];
      }
    }
  }
  float bb[4];
#pragma unroll
  for (int i = 0; i < 4; ++i) bb[i] = B2[c0 + i];
#pragma unroll
  for (int jj = 0; jj < 4; ++jj) {
    int p = p0 + pl + jj;
    __half* o = T2 + (size_t)p * 36 + c0;
    float v0 = acc[jj * 4 + 0] + bb[0];
    float v1 = acc[jj * 4 + 1] + bb[1];
    float v2 = acc[jj * 4 + 2] + bb[2];
    float v3 = acc[jj * 4 + 3] + bb[3];
    __half2 h01, h23;
    h01.x = f2h(v0 > 0.f ? v0 : 0.2f * v0);
    h01.y = f2h(v1 > 0.f ? v1 : 0.2f * v1);
    h23.x = f2h(v2 > 0.f ? v2 : 0.2f * v2);
    h23.y = f2h(v3 > 0.f ? v3 : 0.2f * v3);
    *(__half2*)o = h01;
    *(__half2*)(o + 2) = h23;
  }
}

// ---------------------------------------------------------------------------
// K3 (MFMA): qv = (t2 @ conv3_w + b3) * (x @ dfe_lin_w + bd), stored x64 f16
// windowed. Block: 128 rows x 48 cols; 4 waves x (2 m-tiles x 3 n-tiles) of
// 16x16x32 f16 MFMA. A LDS [128][40] f16, B LDS n-major [48][40] f16.
// Grid: bm = blk & 1023 (M), bn = blk >> 10 (N; same-X blocks share XCD).
// ---------------------------------------------------------------------------
__global__ __launch_bounds__(256) void k3_qv(const float* __restrict__ X,
                                             const __half* __restrict__ T2,
                                             const float* __restrict__ W3,
                                             const float* __restrict__ B3,
                                             const float* __restrict__ WD,
                                             const float* __restrict__ BD,
                                             __half* __restrict__ QX) {
  __shared__ f16 As[128 * 40];
  __shared__ f16 Bs[48 * 40];
  int t = threadIdx.x;
  int bm = blockIdx.x & 1023, bn = blockIdx.x >> 10;
  int p0 = bm * 128, n0 = bn * 48;
  int lane = t & 63, wave = t >> 6;
  int lm = lane & 15, lq = lane >> 4;
  f32x4 accC[2][3], accD[2][3];
#pragma unroll
  for (int i = 0; i < 2; ++i)
#pragma unroll
    for (int j = 0; j < 3; ++j) {
      accC[i][j] = (f32x4){0.f, 0.f, 0.f, 0.f};
      accD[i][j] = (f32x4){0.f, 0.f, 0.f, 0.f};
    }

  // ---- phase 1: accC = T2 @ W3 (K=36, 2 chunks of 32) ----
  for (int ch = 0; ch < 2; ++ch) {
    int kc = ch * 32;
    __syncthreads();
#pragma unroll
    for (int r = 0; r < 4; ++r) {
      int m = (t >> 3) + r * 32;
      int kq = (t & 7) * 4;
      int k0 = kc + kq;
      uint2 val = {0u, 0u};
      if (k0 < 36) val = *(const uint2*)&T2[(size_t)(p0 + m) * 36 + k0];
      *(uint2*)&As[m * 40 + kq] = val;
    }
    for (int i = t; i < 384; i += 256) {
      int k = i / 12, nq = (i % 12) * 4;
      float4 w = {0.f, 0.f, 0.f, 0.f};
      int kk = kc + k;
      if (kk < 36 && n0 + nq < 180)
        w = *(const float4*)&W3[(size_t)kk * 180 + n0 + nq];
      Bs[(nq + 0) * 40 + k] = (f16)w.x;
      Bs[(nq + 1) * 40 + k] = (f16)w.y;
      Bs[(nq + 2) * 40 + k] = (f16)w.z;
      Bs[(nq + 3) * 40 + k] = (f16)w.w;
    }
    __syncthreads();
    f16x8 af[2], bf[3];
#pragma unroll
    for (int mt = 0; mt < 2; ++mt)
      af[mt] = *(const f16x8*)&As[(wave * 32 + mt * 16 + lm) * 40 + lq * 8];
#pragma unroll
    for (int nt = 0; nt < 3; ++nt)
      bf[nt] = *(const f16x8*)&Bs[(nt * 16 + lm) * 40 + lq * 8];
#pragma unroll
    for (int mt = 0; mt < 2; ++mt)
#pragma unroll
      for (int nt = 0; nt < 3; ++nt)
        accC[mt][nt] = __builtin_amdgcn_mfma_f32_16x16x32_f16(
            af[mt], bf[nt], accC[mt][nt], 0, 0, 0);
  }

  // ---- phase 2: accD = X @ WD (K=180, 6 chunks of 32) ----
  for (int ch = 0; ch < 6; ++ch) {
    int kc = ch * 32;
    __syncthreads();
#pragma unroll
    for (int r = 0; r < 4; ++r) {
      int m = (t >> 3) + r * 32;
      int kq = (t & 7) * 4;
      int k0 = kc + kq;
      union { f16 h[4]; uint2 u; } val;
      val.u.x = 0u; val.u.y = 0u;
      if (k0 < 180) {
        float4 x = *(const float4*)&X[(size_t)(p0 + m) * 180 + k0];
        val.h[0] = (f16)x.x; val.h[1] = (f16)x.y;
        val.h[2] = (f16)x.z; val.h[3] = (f16)x.w;
      }
      *(uint2*)&As[m * 40 + kq] = val.u;
    }
    for (int i = t; i < 384; i += 256) {
      int k = i / 12, nq = (i % 12) * 4;
      float4 w = {0.f, 0.f, 0.f, 0.f};
      int kk = kc + k;
      if (kk < 180 && n0 + nq < 180)
        w = *(const float4*)&WD[(size_t)kk * 180 + n0 + nq];
      Bs[(nq + 0) * 40 + k] = (f16)w.x;
      Bs[(nq + 1) * 40 + k] = (f16)w.y;
      Bs[(nq + 2) * 40 + k] = (f16)w.z;
      Bs[(nq + 3) * 40 + k] = (f16)w.w;
    }
    __syncthreads();
    f16x8 af[2], bf[3];
#pragma unroll
    for (int mt = 0; mt < 2; ++mt)
      af[mt] = *(const f16x8*)&As[(wave * 32 + mt * 16 + lm) * 40 + lq * 8];
#pragma unroll
    for (int nt = 0; nt < 3; ++nt)
      bf[nt] = *(const f16x8*)&Bs[(nt * 16 + lm) * 40 + lq * 8];
#pragma unroll
    for (int mt = 0; mt < 2; ++mt)
#pragma unroll
      for (int nt = 0; nt < 3; ++nt)
        accD[mt][nt] = __builtin_amdgcn_mfma_f32_16x16x32_f16(
            af[mt], bf[nt], accD[mt][nt], 0, 0, 0);
  }

  // ---- epilogue: qv = (accC+b3)*(accD+bd)*64, windowed f16 scatter ----
  float cb[3], db[3];
#pragma unroll
  for (int nt = 0; nt < 3; ++nt) {
    int col = n0 + nt * 16 + lm;
    cb[nt] = (col < 180) ? B3[col] : 0.f;
    db[nt] = (col < 180) ? BD[col] : 0.f;
  }
#pragma unroll
  for (int mt = 0; mt < 2; ++mt) {
#pragma unroll
    for (int reg = 0; reg < 4; ++reg) {
      int p = p0 + wave * 32 + mt * 16 + lq * 4 + reg;
      int b = p >> 16, y = (p >> 8) & 255, x = p & 255;
      int wi = (b << 8) | ((y >> 4) << 4) | (x >> 4);
      int l = ((y & 15) << 4) | (x & 15);
      __half* orow = QX + ((size_t)(wi * 256 + l)) * 180;
#pragma unroll
      for (int nt = 0; nt < 3; ++nt) {
        int col = n0 + nt * 16 + lm;
        if (col < 180)
          orow[col] = f2h((accC[mt][nt][reg] + cb[nt]) *
                          (accD[mt][nt][reg] + db[nt]) * 64.f);
      }
    }
  }
}

// ---------------------------------------------------------------------------
// K5a: position-bias MLP over 961 grid points -> PTAB[961][6] f32
// ---------------------------------------------------------------------------
__device__ __forceinline__ void ln_relu11(const float* p, const float* g,
                                          const float* b, float* r) {
  float m = 0.f;
#pragma unroll
  for (int j = 0; j < 11; ++j) m += p[j];
  m *= (1.0f / 11.0f);
  float v = 0.f;
#pragma unroll
  for (int j = 0; j < 11; ++j) { float d = p[j] - m; v += d * d; }
  v *= (1.0f / 11.0f);
  float inv = 1.0f / sqrtf(v + 1e-5f);
#pragma unroll
  for (int j = 0; j < 11; ++j) {
    float xn = (p[j] - m) * inv * g[j] + b[j];
    r[j] = fmaxf(xn, 0.f);
  }
}
__device__ __forceinline__ void mm11(const float* r, const float* W,
                                     const float* b, float* o) {
#pragma unroll
  for (int j2 = 0; j2 < 11; ++j2) {
    float s = b[j2];
#pragma unroll
    for (int j = 0; j < 11; ++j) s += r[j] * W[j * 11 + j2];
    o[j2] = s;
  }
}

__global__ __launch_bounds__(256) void k5a_posmlp(
    const float* PPW, const float* PPB,
    const float* LN1G, const float* LN1B, const float* M1W, const float* M1B,
    const float* LN2G, const float* LN2B, const float* M2W, const float* M2B,
    const float* LN3G, const float* LN3B, const float* M3W, const float* M3B,
    float* __restrict__ PTAB) {
  int t = blockIdx.x * 256 + threadIdx.x;
  if (t >= 961) return;
  float g0 = (float)(t / 31) - 15.0f;
  float g1 = (float)(t % 31) - 15.0f;
  float p[11], r[11];
#pragma unroll
  for (int j = 0; j < 11; ++j)
    p[j] = g0 * PPW[j] + g1 * PPW[11 + j] + PPB[j];
  ln_relu11(p, LN1G, LN1B, r);
  mm11(r, M1W, M1B, p);
  ln_relu11(p, LN2G, LN2B, r);
  mm11(r, M2W, M2B, p);
  ln_relu11(p, LN3G, LN3B, r);
#pragma unroll
  for (int h = 0; h < 6; ++h) {
    float s = M3B[h];
#pragma unroll
    for (int j = 0; j < 11; ++j) s += r[j] * M3W[j * 6 + h];
    PTAB[t * 6 + h] = s;
  }
}

// ---------------------------------------------------------------------------
// K5b: RPB[h][l][m] = mean over 2x2 of PTAB[(dr+15)*31+(dc+15)][h]
// ---------------------------------------------------------------------------
__global__ __launch_bounds__(256) void k5b_rpb(const float* __restrict__ PTAB,
                                               float* __restrict__ RPB) {
  int t = blockIdx.x * 256 + threadIdx.x;  // < 98304
  int m = t & 63;
  int l = (t >> 6) & 255;
  int h = t >> 14;
  int mh = m >> 3, mw = m & 7;
  int qr = l >> 4, qc = l & 15;
  float s = 0.f;
#pragma unroll
  for (int rh = 0; rh < 2; ++rh)
#pragma unroll
    for (int rw = 0; rw < 2; ++rw) {
      int dr = qr - (mh * 2 + rh) + 15;
      int dc = qc - (mw * 2 + rw) + 15;
      s += PTAB[(dr * 31 + dc) * 6 + h];
    }
  RPB[t] = 0.25f * s;
}

// ---------------------------------------------------------------------------
// K7a: cc[wi][c][d] = sum_l q[l][c]*v[l][d] / 256, f32 out (true scale).
// ---------------------------------------------------------------------------
__global__ __launch_bounds__(256) void k7a_cc(const __half* __restrict__ QX,
                                              float* __restrict__ CC) {
  __shared__ __half qs[64 * 90];
  __shared__ __half vs[64 * 90];
  int wi = blockIdx.x, t = threadIdx.x;
  int c0 = (t % 15) * 6, d0 = (t / 15) * 6;
  bool act = t < 225;
  float acc[36];
#pragma unroll
  for (int i = 0; i < 36; ++i) acc[i] = 0.f;
  const uint32* G = (const uint32*)(QX + (size_t)wi * 46080);
  uint32* qsw = (uint32*)qs;
  uint32* vsw = (uint32*)vs;
  for (int pass = 0; pass < 4; ++pass) {
    __syncthreads();
    for (int i = t; i < 2880; i += 256) {
      int l = i / 45, k = i % 45;
      int gw = (pass * 64 + l) * 90;
      qsw[l * 45 + k] = G[gw + k];
      vsw[l * 45 + k] = G[gw + 45 + k];
    }
    __syncthreads();
    if (act) {
      for (int l = 0; l < 64; ++l) {
        const __half2* qh = (const __half2*)&qs[l * 90 + c0];
        const __half2* vh = (const __half2*)&vs[l * 90 + d0];
        float a[6], b[6];
#pragma unroll
        for (int k = 0; k < 3; ++k) {
          __half2 x = qh[k];
          a[2 * k] = __low2float(x); a[2 * k + 1] = __high2float(x);
          __half2 y = vh[k];
          b[2 * k] = __low2float(y); b[2 * k + 1] = __high2float(y);
        }
#pragma unroll
        for (int i = 0; i < 6; ++i)
#pragma unroll
          for (int j = 0; j < 6; ++j) acc[i * 6 + j] += a[i] * b[j];
      }
    }
  }
  if (act) {
    const float s = 1.0f / (256.0f * 4096.0f);
#pragma unroll
    for (int i = 0; i < 6; ++i)
#pragma unroll
      for (int j = 0; j < 6; ++j)
        CC[((size_t)(wi * 90 + c0 + i)) * 90 + d0 + j] = acc[i * 6 + j] * s;
  }
}

// ---------------------------------------------------------------------------
// KA: per window: vp (LDS, x256) from v(x64); corr = q.vp/15 + rpb;
// x_sp written IN PLACE over q-channels as 8192*x_sp (f16).
// ---------------------------------------------------------------------------
__global__ __launch_bounds__(256) void kA_xsp(__half* __restrict__ QX,
                                              const float* __restrict__ RPB,
                                              const float* __restrict__ SLW,
                                              const float* __restrict__ SLB) {
  __shared__ __half vlds[256 * 90];
  __shared__ __half vpT[6 * 15 * 64];
  int wi = blockIdx.x, t = threadIdx.x;
  __half* QW = QX + (size_t)wi * 46080;
  const uint32* G = (const uint32*)QW;
  uint32* VW = (uint32*)vlds;
  for (int i = t; i < 11520; i += 256) {
    int l = i / 45, k = i % 45;
    VW[l * 45 + k] = G[l * 90 + 45 + k];
  }
  __syncthreads();
  float w0 = SLW[0], w1 = SLW[1], w2 = SLW[2], w3 = SLW[3];
  float sb = SLB[0];
  for (int e = t; e < 5760; e += 256) {
    int m = e & 63, c = (e >> 6) % 15, h = e / 960;
    int mh = m >> 3, mw = m & 7, lb = mh * 32 + mw * 2;
    int ch = h * 15 + c;
    float s = w0 * h2f(vlds[lb * 90 + ch]) + w1 * h2f(vlds[(lb + 1) * 90 + ch])
            + w2 * h2f(vlds[(lb + 16) * 90 + ch]) + w3 * h2f(vlds[(lb + 17) * 90 + ch]);
    vpT[ch * 64 + m] = f2h(s * 4.f + sb * 256.f);
  }
  __syncthreads();
  int l = t;
  for (int h = 0; h < 6; ++h) {
    __half* qrow = QW + l * 180 + h * 15;
    float qreg[15];
#pragma unroll
    for (int c = 0; c < 15; ++c) qreg[c] = h2f(qrow[c]);
    float corr[64];
#pragma unroll
    for (int m = 0; m < 64; ++m) corr[m] = 0.f;
    for (int c = 0; c < 15; ++c) {
      float qc = qreg[c];
      const __half2* vp2 = (const __half2*)&vpT[(h * 15 + c) * 64];
#pragma unroll
      for (int m2 = 0; m2 < 32; ++m2) {
        __half2 vv = vp2[m2];
        corr[2 * m2]     += qc * __low2float(vv);
        corr[2 * m2 + 1] += qc * __high2float(vv);
      }
    }
    const float4* rb4 = (const float4*)(RPB + ((size_t)(h * 256 + l)) * 64);
    const float inv = 1.0f / (15.0f * 64.0f * 256.0f);
#pragma unroll
    for (int m4 = 0; m4 < 16; ++m4) {
      float4 rv = rb4[m4];
      corr[4 * m4 + 0] = corr[4 * m4 + 0] * inv + rv.x;
      corr[4 * m4 + 1] = corr[4 * m4 + 1] * inv + rv.y;
      corr[4 * m4 + 2] = corr[4 * m4 + 2] * inv + rv.z;
      corr[4 * m4 + 3] = corr[4 * m4 + 3] * inv + rv.w;
    }
    for (int c = 0; c < 15; ++c) {
      const __half2* vp2 = (const __half2*)&vpT[(h * 15 + c) * 64];
      float s = 0.f;
#pragma unroll
      for (int m2 = 0; m2 < 32; ++m2) {
        __half2 vv = vp2[m2];
        s += corr[2 * m2] * __low2float(vv) + corr[2 * m2 + 1] * __high2float(vv);
      }
      qrow[c] = f2h(s * 32.f);  // 256*x_sp * 32 = 8192*x_sp
    }
  }
}

// ---------------------------------------------------------------------------
// KB: per window: x_ch[l][c] = sum_d cc[c][d]*v[l][d], written IN PLACE over
// v-channels as 8192*x_ch (f16).
// ---------------------------------------------------------------------------
__global__ __launch_bounds__(256) void kB_xch(__half* __restrict__ QX,
                                              const float* __restrict__ CC) {
  __shared__ __half vlds[256 * 90];
  __shared__ __half ccs[90 * 90];    // scaled x65536
  int wi = blockIdx.x, t = threadIdx.x;
  __half* QW = QX + (size_t)wi * 46080;
  const uint32* G = (const uint32*)QW;
  uint32* VW = (uint32*)vlds;
  for (int i = t; i < 11520; i += 256) {
    int l = i / 45, k = i % 45;
    VW[l * 45 + k] = G[l * 90 + 45 + k];
  }
  const float* ccg = CC + (size_t)wi * 8100;
  for (int i = t; i < 8100; i += 256) ccs[i] = f2h(ccg[i] * 65536.f);
  __syncthreads();
  int l = t;
  float vr[90];
  const __half2* v2 = (const __half2*)&vlds[l * 90];
#pragma unroll
  for (int k = 0; k < 45; ++k) {
    __half2 h = v2[k];
    vr[2 * k] = __low2float(h); vr[2 * k + 1] = __high2float(h);
  }
  __half* orow = QW + l * 180 + 90;
  for (int c = 0; c < 90; ++c) {
    const __half2* cr = (const __half2*)&ccs[c * 90];
    float s = 0.f;
#pragma unroll
    for (int k = 0; k < 45; ++k) {
      __half2 h = cr[k];
      s += vr[2 * k] * __low2float(h) + vr[2 * k + 1] * __high2float(h);
    }
    // s = 2^22 * x_ch ; store 2^13 * x_ch
    orow[c] = f2h(s * 0.001953125f);
  }
}

// ---------------------------------------------------------------------------
// K8 (MFMA): out = (XS/8192) @ proj_w + proj_b, f32 out, window-reverse
// scatter. Same tiling as k3: 128x48 block, 16x16x32 f16 MFMA, K=180.
// ---------------------------------------------------------------------------
__global__ __launch_bounds__(256) void k8_proj(const __half* __restrict__ XS,
                                               const float* __restrict__ PW,
                                               const float* __restrict__ PB,
                                               float* __restrict__ OUT) {
  __shared__ f16 As[128 * 40];
  __shared__ f16 Bs[48 * 40];
  int t = threadIdx.x;
  int bm = blockIdx.x & 1023, bn = blockIdx.x >> 10;
  int w0r = bm * 128, n0 = bn * 48;
  int lane = t & 63, wave = t >> 6;
  int lm = lane & 15, lq = lane >> 4;
  f32x4 acc[2][3];
#pragma unroll
  for (int i = 0; i < 2; ++i)
#pragma unroll
    for (int j = 0; j < 3; ++j) acc[i][j] = (f32x4){0.f, 0.f, 0.f, 0.f};

  for (int ch = 0; ch < 6; ++ch) {
    int kc = ch * 32;
    __syncthreads();
#pragma unroll
    for (int r = 0; r < 4; ++r) {
      int m = (t >> 3) + r * 32;
      int kq = (t & 7) * 4;
      int k0 = kc + kq;
      uint2 val = {0u, 0u};
      if (k0 < 180) val = *(const uint2*)&XS[(size_t)(w0r + m) * 180 + k0];
      *(uint2*)&As[m * 40 + kq] = val;
    }
    for (int i = t; i < 384; i += 256) {
      int k = i / 12, nq = (i % 12) * 4;
      float4 w = {0.f, 0.f, 0.f, 0.f};
      int kk = kc + k;
      if (kk < 180 && n0 + nq < 180)
        w = *(const float4*)&PW[(size_t)kk * 180 + n0 + nq];
      Bs[(nq + 0) * 40 + k] = (f16)w.x;
      Bs[(nq + 1) * 40 + k] = (f16)w.y;
      Bs[(nq + 2) * 40 + k] = (f16)w.z;
      Bs[(nq + 3) * 40 + k] = (f16)w.w;
    }
    __syncthreads();
    f16x8 af[2], bf[3];
#pragma unroll
    for (int mt = 0; mt < 2; ++mt)
      af[mt] = *(const f16x8*)&As[(wave * 32 + mt * 16 + lm) * 40 + lq * 8];
#pragma unroll
    for (int nt = 0; nt < 3; ++nt)
      bf[nt] = *(const f16x8*)&Bs[(nt * 16 + lm) * 40 + lq * 8];
#pragma unroll
    for (int mt = 0; mt < 2; ++mt)
#pragma unroll
      for (int nt = 0; nt < 3; ++nt)
        acc[mt][nt] = __builtin_amdgcn_mfma_f32_16x16x32_f16(
            af[mt], bf[nt], acc[mt][nt], 0, 0, 0);
  }

  float pb[3];
#pragma unroll
  for (int nt = 0; nt < 3; ++nt) {
    int col = n0 + nt * 16 + lm;
    pb[nt] = (col < 180) ? PB[col] : 0.f;
  }
  const float inv = 1.0f / 8192.0f;
#pragma unroll
  for (int mt = 0; mt < 2; ++mt) {
#pragma unroll
    for (int reg = 0; reg < 4; ++reg) {
      int w = w0r + wave * 32 + mt * 16 + lq * 4 + reg;
      int wi = w >> 8, l = w & 255;
      int b = wi >> 8, wy = (wi >> 4) & 15, wx = wi & 15;
      int ly = l >> 4, lx = l & 15;
      int p = (b << 16) | (((wy << 4) | ly) << 8) | ((wx << 4) | lx);
      float* orow = OUT + (size_t)p * 180;
#pragma unroll
      for (int nt = 0; nt < 3; ++nt) {
        int col = n0 + nt * 16 + lm;
        if (col < 180) orow[col] = acc[mt][nt][reg] * inv + pb[nt];
      }
    }
  }
}

// ---------------------------------------------------------------------------
// Workspace layout (bytes) — peak requirement 66,060,288 (63.0 MB):
//  QX  f16 [512][256][180]  @ 0            (47,185,920)  qv*64 -> XS in place
//  T1  f16 [131072][36]     @ 47,185,920   ( 9,437,184)  dead after k2
//  T2  f16 [131072][36]     @ 56,623,104   ( 9,437,184)  dead after k3
//  PTAB f32 [961*6]         @ 47,185,920   over dead T1
//  RPB  f32 [6][256][64]    @ 47,212,544   over dead T1
//  CC   f32 [512][90][90]   @ 47,605,760   over dead T1/T2
// ---------------------------------------------------------------------------
extern "C" void kernel_launch(void* const* d_in, const int* in_sizes, int n_in,
                              void* d_out, int out_size, void* d_ws, size_t ws_size,
                              hipStream_t stream) {
  const float* X    = (const float*)d_in[0];
  const float* W1   = (const float*)d_in[1];
  const float* B1   = (const float*)d_in[2];
  const float* W2   = (const float*)d_in[3];
  const float* B2   = (const float*)d_in[4];
  const float* W3   = (const float*)d_in[5];
  const float* B3c  = (const float*)d_in[6];
  const float* WD   = (const float*)d_in[7];
  const float* BD   = (const float*)d_in[8];
  const float* SLW  = (const float*)d_in[9];
  const float* SLB  = (const float*)d_in[10];
  const float* PPW  = (const float*)d_in[11];
  const float* PPB  = (const float*)d_in[12];
  const float* LN1G = (const float*)d_in[13];
  const float* LN1B = (const float*)d_in[14];
  const float* M1W  = (const float*)d_in[15];
  const float* M1B  = (const float*)d_in[16];
  const float* LN2G = (const float*)d_in[17];
  const float* LN2B = (const float*)d_in[18];
  const float* M2W  = (const float*)d_in[19];
  const float* M2B  = (const float*)d_in[20];
  const float* LN3G = (const float*)d_in[21];
  const float* LN3B = (const float*)d_in[22];
  const float* M3W  = (const float*)d_in[23];
  const float* M3B  = (const float*)d_in[24];
  const float* PW   = (const float*)d_in[25];
  const float* PB   = (const float*)d_in[26];
  float* OUT = (float*)d_out;

  char* ws = (char*)d_ws;
  __half* QX  = (__half*)(ws);
  __half* T1  = (__half*)(ws + 47185920);
  __half* T2  = (__half*)(ws + 56623104);
  float* PTAB = (float*)(ws + 47185920);
  float* RPB  = (float*)(ws + 47212544);
  float* CC   = (float*)(ws + 47605760);

  hipLaunchKernelGGL(k1_conv1, dim3(1024), dim3(256), 0, stream, X, W1, B1, T1);
  hipLaunchKernelGGL(k2_conv2, dim3(2048), dim3(256), 0, stream, T1, W2, B2, T2);
  hipLaunchKernelGGL(k3_qv, dim3(4096), dim3(256), 0, stream, X, T2, W3, B3c, WD, BD, QX);
  hipLaunchKernelGGL(k5a_posmlp, dim3(4), dim3(256), 0, stream,
                     PPW, PPB, LN1G, LN1B, M1W, M1B, LN2G, LN2B, M2W, M2B,
                     LN3G, LN3B, M3W, M3B, PTAB);
  hipLaunchKernelGGL(k5b_rpb, dim3(384), dim3(256), 0, stream, PTAB, RPB);
  hipLaunchKernelGGL(k7a_cc, dim3(512), dim3(256), 0, stream, QX, CC);
  hipLaunchKernelGGL(kA_xsp, dim3(512), dim3(256), 0, stream, QX, RPB, SLW, SLB);
  hipLaunchKernelGGL(kB_xch, dim3(512), dim3(256), 0, stream, QX, CC);
  hipLaunchKernelGGL(k8_proj, dim3(4096), dim3(256), 0, stream, QX, PW, PB, OUT);
}